// Round 1
// baseline (335.111 us; speedup 1.0000x reference)
//
#include <hip/hip_runtime.h>
#include <stdint.h>

#define GENOMES 8
#define BATCH 2
#define SEQ 2048
#define EMBED 1024
#define KVD 256              // KV_HEADS * HEAD_DIM
#define M_PER_G (BATCH*SEQ)  // 4096

typedef float f32x4 __attribute__((ext_vector_type(4)));
typedef __bf16 bf16x8 __attribute__((ext_vector_type(8)));
typedef short s16x8 __attribute__((ext_vector_type(8)));
typedef short s16x4 __attribute__((ext_vector_type(4)));

static __device__ __forceinline__ unsigned short f2bf(float f) {
  unsigned int u = __builtin_bit_cast(unsigned int, f);
  u += 0x7FFFu + ((u >> 16) & 1u);   // round-to-nearest-even
  return (unsigned short)(u >> 16);
}

// async 16B global->LDS. LDS dest must be wave-uniform; HW writes base+lane*16.
static __device__ __forceinline__ void gll16(const void* g, void* l) {
  __builtin_amdgcn_global_load_lds(
      (const __attribute__((address_space(1))) unsigned int*)g,
      (__attribute__((address_space(3))) unsigned int*)l, 16, 0, 0);
}

// ---------------------------------------------------------------------------
// Wv (g, 1024, 256) fp32  ->  WvT (g, 256, 1024) bf16   (B^T layout for GEMM1)
// ---------------------------------------------------------------------------
__global__ __launch_bounds__(256) void wvt_kernel(const float* __restrict__ Wv,
                                                  unsigned short* __restrict__ WvT) {
  int g = blockIdx.y;
  int it = blockIdx.x >> 2;          // 16 i-tiles of 64
  int ot = blockIdx.x & 3;           // 4 o-tiles of 64
  int i0 = it * 64, o0 = ot * 64;
  const float* W = Wv + (size_t)g * EMBED * KVD;
  unsigned short* T = WvT + (size_t)g * KVD * EMBED;
  __shared__ unsigned short tl[64][65];
  int t = threadIdx.x;
  int rr = t >> 4;            // 0..15
  int cc = (t & 15) * 4;      // 0..60
#pragma unroll
  for (int p = 0; p < 4; ++p) {
    int r = rr + p * 16;
    float4 v = *(const float4*)(W + (size_t)(i0 + r) * KVD + o0 + cc);
    tl[r][cc + 0] = f2bf(v.x);
    tl[r][cc + 1] = f2bf(v.y);
    tl[r][cc + 2] = f2bf(v.z);
    tl[r][cc + 3] = f2bf(v.w);
  }
  __syncthreads();
#pragma unroll
  for (int p = 0; p < 4; ++p) {
    int o = rr + p * 16;
    s16x4 v;
    v[0] = (short)tl[cc + 0][o];
    v[1] = (short)tl[cc + 1][o];
    v[2] = (short)tl[cc + 2][o];
    v[3] = (short)tl[cc + 3][o];
    *(s16x4*)(T + (size_t)(o0 + o) * EMBED + i0 + cc) = v;
  }
}

// ---------------------------------------------------------------------------
// Wo (g, 1024, 1024) fp32 -> RT (g, 1024, 256) bf16
// RT[o][kh*64+d] = 64 * sum_{r=0..3} Wo[kh*256 + r*64 + d][o]
// (head-broadcast folded into Wo, x64 softmax-sum factor folded in, transposed)
// ---------------------------------------------------------------------------
__global__ __launch_bounds__(256) void rt_kernel(const float* __restrict__ Wo,
                                                 unsigned short* __restrict__ RT) {
  int g = blockIdx.y;
  int ot = blockIdx.x >> 2;          // 16 o-tiles of 64
  int kh = blockIdx.x & 3;           // 4 kv heads
  int o0 = ot * 64;
  const float* W = Wo + (size_t)g * EMBED * EMBED;
  unsigned short* T = RT + (size_t)g * EMBED * KVD;
  __shared__ float tl[64][65];
  int t = threadIdx.x;
  int rr = t >> 4;
  int cc = (t & 15) * 4;
#pragma unroll
  for (int p = 0; p < 4; ++p) {
    int d = rr + p * 16;
    float a0 = 0.f, a1 = 0.f, a2 = 0.f, a3 = 0.f;
#pragma unroll
    for (int r = 0; r < 4; ++r) {
      float4 v = *(const float4*)(W + (size_t)(kh * 256 + r * 64 + d) * EMBED + o0 + cc);
      a0 += v.x; a1 += v.y; a2 += v.z; a3 += v.w;
    }
    tl[d][cc + 0] = a0; tl[d][cc + 1] = a1; tl[d][cc + 2] = a2; tl[d][cc + 3] = a3;
  }
  __syncthreads();
#pragma unroll
  for (int p = 0; p < 4; ++p) {
    int o = rr + p * 16;
    s16x4 v;
    v[0] = (short)f2bf(64.f * tl[cc + 0][o]);
    v[1] = (short)f2bf(64.f * tl[cc + 1][o]);
    v[2] = (short)f2bf(64.f * tl[cc + 2][o]);
    v[3] = (short)f2bf(64.f * tl[cc + 3][o]);
    *(s16x4*)(T + (size_t)(o0 + o) * KVD + kh * 64 + cc) = v;
  }
}

// ---------------------------------------------------------------------------
// C[M,N] = A[M,K] * Bt[N,K]^T   (per genome in blockIdx.y)
// 128x64 tile, BK=32, 256 threads = 4 waves, each wave owns a 32x64 strip.
// All staging via global_load_lds(16B), double-buffered, 1-deep prefetch.
// LDS XOR-swizzled (both sides: pre-swizzled global source + swizzled ds_read).
// A either fp32 (staged raw f32, converted to bf16 at fragment time) or bf16.
// ---------------------------------------------------------------------------
template <bool A_F32, bool OUT_BF16, int M, int N, int K>
__global__ __launch_bounds__(256) void gemm_bt(const void* __restrict__ Aall,
                                               const unsigned short* __restrict__ Btall,
                                               void* __restrict__ Call) {
  constexpr int BM = 128, BN = 64, BK = 32;
  constexpr int ABYTES = A_F32 ? BM * BK * 4 : BM * BK * 2;  // 16K or 8K
  constexpr int SB = ABYTES + BN * BK * 2;                   // + 4K for B
  constexpr int NTN = N / BN;
  constexpr int NWG = (M / BM) * NTN;
  constexpr int NT = K / BK;
  static_assert(NWG % 8 == 0, "XCD swizzle needs nwg%8==0");

  __shared__ __align__(16) unsigned char smem[2 * SB];

  int g = blockIdx.y;
  int bid = blockIdx.x;
  // bijective XCD swizzle: each XCD gets a contiguous chunk of logical tiles,
  // so the n-blocks sharing an A-panel co-reside in one XCD's L2.
  int lt = (bid & 7) * (NWG >> 3) + (bid >> 3);
  int bm = lt / NTN, bn = lt % NTN;
  int m0 = bm * BM, n0 = bn * BN;

  const unsigned short* Bt = Btall + (size_t)g * N * K;
  const float* Af = (const float*)Aall + (size_t)g * M * K;
  const unsigned short* Ab = (const unsigned short*)Aall + (size_t)g * M * K;

  int tid = threadIdx.x;
  int lane = tid & 63, wave = tid >> 6;
  int lm = lane & 15, quad = lane >> 4;
  int wm = wave * 32;  // wave's m-strip

  // ---- per-thread pre-swizzled staging sources ----
  // LDS image is linear [row][chunk16B]; data chunk c lives at slot c ^ (row & (CH-1)).
  // global_load_lds writes slot (lane%CH) for row (base + lane/CH), so the lane
  // fetches global chunk (lane%CH) ^ (row & (CH-1)).
  const float* srcAf = nullptr;
  const unsigned short* srcAb = nullptr;
  if constexpr (A_F32) {  // 8 chunks/row (128B)
    int rA = wave * 8 + (lane >> 3);
    int cA = (lane & 7) ^ ((lane >> 3) & 7);
    srcAf = Af + (size_t)(m0 + rA) * K + cA * 4;
  } else {                // 4 chunks/row (64B)
    int rA = wave * 16 + (lane >> 2);
    int cA = (lane & 3) ^ ((lane >> 2) & 3);
    srcAb = Ab + (size_t)(m0 + rA) * K + cA * 8;
  }
  int rB = wave * 16 + (lane >> 2);
  int cB = (lane & 3) ^ ((lane >> 2) & 3);
  const unsigned short* srcB = Bt + (size_t)(n0 + rB) * K + cB * 8;

  // ---- fragment LDS byte offsets (swizzled reads) ----
  int offA[2][2];
  int offB[4];
#pragma unroll
  for (int i = 0; i < 2; ++i) {
    if constexpr (A_F32) {
#pragma unroll
      for (int u = 0; u < 2; ++u)
        offA[i][u] = (wm + i * 16 + lm) * 128 + (((2 * quad + u) ^ (lm & 7)) * 16);
    } else {
      offA[i][0] = (wm + i * 16 + lm) * 64 + ((quad ^ (lm & 3)) * 16);
    }
  }
#pragma unroll
  for (int j = 0; j < 4; ++j)
    offB[j] = ABYTES + (j * 16 + lm) * 64 + ((quad ^ (lm & 3)) * 16);

  f32x4 acc[2][4] = {};

  auto stage = [&](int buf, int t) {
    unsigned char* db = smem + buf * SB;
    if constexpr (A_F32) {
      const float* s = srcAf + t * BK;
#pragma unroll
      for (int p = 0; p < 4; ++p)
        gll16(s + (size_t)p * 32 * K, db + p * 4096 + wave * 1024);
    } else {
      const unsigned short* s = srcAb + t * BK;
#pragma unroll
      for (int p = 0; p < 2; ++p)
        gll16(s + (size_t)p * 64 * K, db + p * 4096 + wave * 1024);
    }
    gll16(srcB + t * BK, db + ABYTES + wave * 1024);
  };

  stage(0, 0);
  __syncthreads();  // drains vmcnt(0): tile 0 resident

  for (int t = 0; t < NT; ++t) {
    if (t + 1 < NT) stage((t + 1) & 1, t + 1);  // async prefetch next tile

    const unsigned char* db = smem + (t & 1) * SB;
    bf16x8 a[2], b[4];
    if constexpr (A_F32) {
#pragma unroll
      for (int i = 0; i < 2; ++i) {
        f32x4 lo = *(const f32x4*)(db + offA[i][0]);
        f32x4 hi = *(const f32x4*)(db + offA[i][1]);
#pragma unroll
        for (int u = 0; u < 4; ++u) {
          a[i][u] = (__bf16)lo[u];
          a[i][4 + u] = (__bf16)hi[u];
        }
      }
    } else {
#pragma unroll
      for (int i = 0; i < 2; ++i)
        a[i] = __builtin_bit_cast(bf16x8, *(const s16x8*)(db + offA[i][0]));
    }
#pragma unroll
    for (int j = 0; j < 4; ++j)
      b[j] = __builtin_bit_cast(bf16x8, *(const s16x8*)(db + offB[j]));

#pragma unroll
    for (int i = 0; i < 2; ++i)
#pragma unroll
      for (int j = 0; j < 4; ++j)
        acc[i][j] = __builtin_amdgcn_mfma_f32_16x16x32_bf16(a[i], b[j], acc[i][j], 0, 0, 0);

    __syncthreads();  // drains prefetch vmcnt + protects buffer reuse
  }

  // ---- epilogue: C/D layout col=lane&15, row=quad*4+reg ----
  if constexpr (OUT_BF16) {
    unsigned short* C = (unsigned short*)Call + (size_t)g * M * N;
#pragma unroll
    for (int i = 0; i < 2; ++i)
#pragma unroll
      for (int j = 0; j < 4; ++j)
#pragma unroll
        for (int r = 0; r < 4; ++r) {
          int mm = m0 + wm + i * 16 + quad * 4 + r;
          int nn = n0 + j * 16 + lm;
          C[(size_t)mm * N + nn] = f2bf(acc[i][j][r]);
        }
  } else {
    float* C = (float*)Call + (size_t)g * M * N;
#pragma unroll
    for (int i = 0; i < 2; ++i)
#pragma unroll
      for (int j = 0; j < 4; ++j)
#pragma unroll
        for (int r = 0; r < 4; ++r) {
          int mm = m0 + wm + i * 16 + quad * 4 + r;
          int nn = n0 + j * 16 + lm;
          C[(size_t)mm * N + nn] = acc[i][j][r];
        }
  }
}

// ---------------------------------------------------------------------------
extern "C" void kernel_launch(void* const* d_in, const int* in_sizes, int n_in,
                              void* d_out, int out_size, void* d_ws, size_t ws_size,
                              hipStream_t stream) {
  const float* tensor = (const float*)d_in[0];
  // d_in[1] = Wq, d_in[2] = Wk: dead code in the reference (einsum contracts them out)
  const float* Wv = (const float*)d_in[3];
  const float* Wo = (const float*)d_in[4];
  float* out = (float*)d_out;

  unsigned short* WvT = (unsigned short*)d_ws;                       //  4 MB
  unsigned short* RT  = WvT + (size_t)GENOMES * KVD * EMBED;         //  4 MB
  unsigned short* V   = RT  + (size_t)GENOMES * EMBED * KVD;         // 16 MB

  // prep: transpose/convert Wv, fold+transpose/convert Wo
  wvt_kernel<<<dim3(64, GENOMES), 256, 0, stream>>>(Wv, WvT);
  rt_kernel<<<dim3(64, GENOMES), 256, 0, stream>>>(Wo, RT);

  // GEMM1: V[g] (4096x256 bf16) = tensor[g] (4096x1024 fp32) @ WvT^T
  gemm_bt<true, true, M_PER_G, KVD, EMBED>
      <<<dim3((M_PER_G / 128) * (KVD / 64), GENOMES), 256, 0, stream>>>(tensor, WvT, V);

  // GEMM2: out[g] (4096x1024 fp32) = V[g] (4096x256 bf16) @ RT^T   (x64 folded into RT)
  gemm_bt<false, false, M_PER_G, EMBED, KVD>
      <<<dim3((M_PER_G / 128) * (EMBED / 64), GENOMES), 256, 0, stream>>>(V, RT, out);
}

// Round 2
// 326.242 us; speedup vs baseline: 1.0272x; 1.0272x over previous
//
#include <hip/hip_runtime.h>
#include <stdint.h>

#define GENOMES 8
#define BATCH 2
#define SEQ 2048
#define EMBED 1024
#define KVD 256              // KV_HEADS * HEAD_DIM
#define M_PER_G (BATCH*SEQ)  // 4096

typedef float f32x4 __attribute__((ext_vector_type(4)));
typedef __bf16 bf16x8 __attribute__((ext_vector_type(8)));
typedef short s16x8 __attribute__((ext_vector_type(8)));
typedef short s16x4 __attribute__((ext_vector_type(4)));

static __device__ __forceinline__ unsigned short f2bf(float f) {
  unsigned int u = __builtin_bit_cast(unsigned int, f);
  u += 0x7FFFu + ((u >> 16) & 1u);   // round-to-nearest-even
  return (unsigned short)(u >> 16);
}

// async 16B global->LDS. LDS dest must be wave-uniform; HW writes base+lane*16.
static __device__ __forceinline__ void gll16(const void* g, void* l) {
  __builtin_amdgcn_global_load_lds(
      (const __attribute__((address_space(1))) unsigned int*)g,
      (__attribute__((address_space(3))) unsigned int*)l, 16, 0, 0);
}

// counted vmcnt wait, compiler memory fence both directions
#define WAITVM(n) asm volatile("s_waitcnt vmcnt(" #n ")" ::: "memory")
#define MEMFENCE() asm volatile("" ::: "memory")

// ---------------------------------------------------------------------------
// Wv (g, 1024, 256) fp32  ->  WvT (g, 256, 1024) bf16   (B^T layout for GEMM1)
// ---------------------------------------------------------------------------
__global__ __launch_bounds__(256) void wvt_kernel(const float* __restrict__ Wv,
                                                  unsigned short* __restrict__ WvT) {
  int g = blockIdx.y;
  int it = blockIdx.x >> 2;          // 16 i-tiles of 64
  int ot = blockIdx.x & 3;           // 4 o-tiles of 64
  int i0 = it * 64, o0 = ot * 64;
  const float* W = Wv + (size_t)g * EMBED * KVD;
  unsigned short* T = WvT + (size_t)g * KVD * EMBED;
  __shared__ unsigned short tl[64][65];
  int t = threadIdx.x;
  int rr = t >> 4;            // 0..15
  int cc = (t & 15) * 4;      // 0..60
#pragma unroll
  for (int p = 0; p < 4; ++p) {
    int r = rr + p * 16;
    float4 v = *(const float4*)(W + (size_t)(i0 + r) * KVD + o0 + cc);
    tl[r][cc + 0] = f2bf(v.x);
    tl[r][cc + 1] = f2bf(v.y);
    tl[r][cc + 2] = f2bf(v.z);
    tl[r][cc + 3] = f2bf(v.w);
  }
  __syncthreads();
#pragma unroll
  for (int p = 0; p < 4; ++p) {
    int o = rr + p * 16;
    s16x4 v;
    v[0] = (short)tl[cc + 0][o];
    v[1] = (short)tl[cc + 1][o];
    v[2] = (short)tl[cc + 2][o];
    v[3] = (short)tl[cc + 3][o];
    *(s16x4*)(T + (size_t)(o0 + o) * EMBED + i0 + cc) = v;
  }
}

// ---------------------------------------------------------------------------
// Wo (g, 1024, 1024) fp32 -> RT (g, 1024, 256) bf16
// RT[o][kh*64+d] = 64 * sum_{r=0..3} Wo[kh*256 + r*64 + d][o]
// ---------------------------------------------------------------------------
__global__ __launch_bounds__(256) void rt_kernel(const float* __restrict__ Wo,
                                                 unsigned short* __restrict__ RT) {
  int g = blockIdx.y;
  int ot = blockIdx.x >> 2;          // 16 o-tiles of 64
  int kh = blockIdx.x & 3;           // 4 kv heads
  int o0 = ot * 64;
  const float* W = Wo + (size_t)g * EMBED * EMBED;
  unsigned short* T = RT + (size_t)g * EMBED * KVD;
  __shared__ float tl[64][65];
  int t = threadIdx.x;
  int rr = t >> 4;
  int cc = (t & 15) * 4;
#pragma unroll
  for (int p = 0; p < 4; ++p) {
    int d = rr + p * 16;
    float a0 = 0.f, a1 = 0.f, a2 = 0.f, a3 = 0.f;
#pragma unroll
    for (int r = 0; r < 4; ++r) {
      float4 v = *(const float4*)(W + (size_t)(kh * 256 + r * 64 + d) * EMBED + o0 + cc);
      a0 += v.x; a1 += v.y; a2 += v.z; a3 += v.w;
    }
    tl[d][cc + 0] = a0; tl[d][cc + 1] = a1; tl[d][cc + 2] = a2; tl[d][cc + 3] = a3;
  }
  __syncthreads();
#pragma unroll
  for (int p = 0; p < 4; ++p) {
    int o = rr + p * 16;
    s16x4 v;
    v[0] = (short)f2bf(64.f * tl[cc + 0][o]);
    v[1] = (short)f2bf(64.f * tl[cc + 1][o]);
    v[2] = (short)f2bf(64.f * tl[cc + 2][o]);
    v[3] = (short)f2bf(64.f * tl[cc + 3][o]);
    *(s16x4*)(T + (size_t)(o0 + o) * KVD + kh * 64 + cc) = v;
  }
}

// ---------------------------------------------------------------------------
// C[M,N] = A[M,K] * Bt[N,K]^T   (per genome in blockIdx.y)
// 128x64 tile, BK=32, 256 threads = 4 waves, each wave owns a 32x64 strip.
// 4-deep ring of LDS stage buffers, counted vmcnt (never 0 in main loop),
// ONE raw s_barrier per K-step. All staging via global_load_lds(16B) with
// pre-swizzled global sources (bank-conflict-free swizzled reads).
// ---------------------------------------------------------------------------
template <bool A_F32, bool OUT_BF16, int M, int N, int K>
__global__ __launch_bounds__(256) void gemm_bt(const void* __restrict__ Aall,
                                               const unsigned short* __restrict__ Btall,
                                               void* __restrict__ Call) {
  constexpr int BM = 128, BN = 64, BK = 32;
  constexpr int ABYTES = A_F32 ? BM * BK * 4 : BM * BK * 2;  // 16K or 8K
  constexpr int SB = ABYTES + BN * BK * 2;                   // + 4K for B
  constexpr int NTN = N / BN;
  constexpr int NWG = (M / BM) * NTN;
  constexpr int NT = K / BK;                                 // 32 or 8
  static_assert(NWG % 8 == 0, "XCD swizzle needs nwg%8==0");
  static_assert(NT >= 4, "pipeline depth 4 needs NT>=4");

  __shared__ __align__(16) unsigned char smem[4 * SB];       // 80K or 48K

  int g = blockIdx.y;
  int bid = blockIdx.x;
  // bijective XCD swizzle: each XCD gets a contiguous chunk of logical tiles.
  int lt = (bid & 7) * (NWG >> 3) + (bid >> 3);
  int bm = lt / NTN, bn = lt % NTN;
  int m0 = bm * BM, n0 = bn * BN;

  const unsigned short* Bt = Btall + (size_t)g * N * K;
  const float* Af = (const float*)Aall + (size_t)g * M * K;
  const unsigned short* Ab = (const unsigned short*)Aall + (size_t)g * M * K;

  int tid = threadIdx.x;
  int lane = tid & 63, wave = tid >> 6;
  int lm = lane & 15, quad = lane >> 4;
  int wm = wave * 32;  // wave's m-strip

  // ---- per-thread pre-swizzled staging sources ----
  // f32 rows (128B = 8 chunks): data chunk c of row r lives at slot c ^ (r&7)
  // bf16 rows (64B = 4 chunks): data chunk c of row r lives at slot c ^ ((r>>1)&3)
  //   ((r>>1)&3 makes bank-quads distinct across each 8-consecutive-lane
  //    service group of the b128 read; (r&3) left 2-way pairs -> 4.2M conflicts)
  const float* srcAf = nullptr;
  const unsigned short* srcAb = nullptr;
  if constexpr (A_F32) {
    int rA = wave * 8 + (lane >> 3);
    int cA = (lane & 7) ^ (rA & 7);
    srcAf = Af + (size_t)(m0 + rA) * K + cA * 4;
  } else {
    int rA = wave * 16 + (lane >> 2);
    int cA = (lane & 3) ^ ((rA >> 1) & 3);
    srcAb = Ab + (size_t)(m0 + rA) * K + cA * 8;
  }
  int rB = wave * 16 + (lane >> 2);
  int cB = (lane & 3) ^ ((rB >> 1) & 3);
  const unsigned short* srcB = Bt + (size_t)(n0 + rB) * K + cB * 8;

  // ---- fragment LDS byte offsets (swizzled reads, within one stage buffer) ----
  int offA[2][2];
  int offB[4];
#pragma unroll
  for (int i = 0; i < 2; ++i) {
    if constexpr (A_F32) {
#pragma unroll
      for (int u = 0; u < 2; ++u)
        offA[i][u] = (wm + i * 16 + lm) * 128 + (((2 * quad + u) ^ (lm & 7)) * 16);
    } else {
      offA[i][0] = (wm + i * 16 + lm) * 64 + ((quad ^ ((lm >> 1) & 3)) * 16);
    }
  }
#pragma unroll
  for (int j = 0; j < 4; ++j)
    offB[j] = ABYTES + (j * 16 + lm) * 64 + ((quad ^ ((lm >> 1) & 3)) * 16);

  f32x4 acc[2][4] = {};

  auto stage = [&](int slot, int t) {
    unsigned char* db = smem + slot * SB;
    if constexpr (A_F32) {
      const float* s = srcAf + t * BK;
#pragma unroll
      for (int p = 0; p < 4; ++p)
        gll16(s + (size_t)p * 32 * K, db + p * 4096 + wave * 1024);
    } else {
      const unsigned short* s = srcAb + t * BK;
#pragma unroll
      for (int p = 0; p < 2; ++p)
        gll16(s + (size_t)p * 64 * K, db + p * 4096 + wave * 1024);
    }
    gll16(srcB + t * BK, db + ABYTES + wave * 1024);
  };

  // body of one K-step: reads(t) -> issue stage(t+3) -> MFMA(t).
  // issue AFTER the barrier: barrier(t) proves all waves finished reads(t-1)
  // on slot (t+3)%4 == (t-1)%4, so overwrite is safe with a single barrier.
  auto iter_body = [&](int t) {
    const unsigned char* db = smem + (t & 3) * SB;
    bf16x8 a[2], b[4];
    if constexpr (A_F32) {
#pragma unroll
      for (int i = 0; i < 2; ++i) {
        f32x4 lo = *(const f32x4*)(db + offA[i][0]);
        f32x4 hi = *(const f32x4*)(db + offA[i][1]);
#pragma unroll
        for (int u = 0; u < 4; ++u) {
          a[i][u] = (__bf16)lo[u];
          a[i][4 + u] = (__bf16)hi[u];
        }
      }
    } else {
#pragma unroll
      for (int i = 0; i < 2; ++i)
        a[i] = __builtin_bit_cast(bf16x8, *(const s16x8*)(db + offA[i][0]));
    }
#pragma unroll
    for (int j = 0; j < 4; ++j)
      b[j] = __builtin_bit_cast(bf16x8, *(const s16x8*)(db + offB[j]));

    if (t + 3 < NT) stage((t + 3) & 3, t + 3);

#pragma unroll
    for (int i = 0; i < 2; ++i)
#pragma unroll
      for (int j = 0; j < 4; ++j)
        acc[i][j] = __builtin_amdgcn_mfma_f32_16x16x32_bf16(a[i], b[j], acc[i][j], 0, 0, 0);
  };

  // prologue: fill 3 pipeline stages
  stage(0, 0);
  stage(1, 1);
  stage(2, 2);

  // main loop: keep 2 stages (2L loads) in flight ACROSS the barrier
  for (int t = 0; t < NT - 2; ++t) {
    if constexpr (A_F32) WAITVM(10); else WAITVM(6);   // 2L
    __builtin_amdgcn_s_barrier();
    MEMFENCE();
    iter_body(t);
  }
  {  // t = NT-2: one stage left in flight
    if constexpr (A_F32) WAITVM(5); else WAITVM(3);    // L
    __builtin_amdgcn_s_barrier();
    MEMFENCE();
    iter_body(NT - 2);
  }
  {  // t = NT-1: full drain
    WAITVM(0);
    __builtin_amdgcn_s_barrier();
    MEMFENCE();
    iter_body(NT - 1);
  }

  // ---- epilogue: C/D layout col=lane&15, row=quad*4+reg ----
  if constexpr (OUT_BF16) {
    unsigned short* C = (unsigned short*)Call + (size_t)g * M * N;
#pragma unroll
    for (int i = 0; i < 2; ++i)
#pragma unroll
      for (int j = 0; j < 4; ++j)
#pragma unroll
        for (int r = 0; r < 4; ++r) {
          int mm = m0 + wm + i * 16 + quad * 4 + r;
          int nn = n0 + j * 16 + lm;
          C[(size_t)mm * N + nn] = f2bf(acc[i][j][r]);
        }
  } else {
    float* C = (float*)Call + (size_t)g * M * N;
#pragma unroll
    for (int i = 0; i < 2; ++i)
#pragma unroll
      for (int j = 0; j < 4; ++j)
#pragma unroll
        for (int r = 0; r < 4; ++r) {
          int mm = m0 + wm + i * 16 + quad * 4 + r;
          int nn = n0 + j * 16 + lm;
          C[(size_t)mm * N + nn] = acc[i][j][r];
        }
  }
}

// ---------------------------------------------------------------------------
extern "C" void kernel_launch(void* const* d_in, const int* in_sizes, int n_in,
                              void* d_out, int out_size, void* d_ws, size_t ws_size,
                              hipStream_t stream) {
  const float* tensor = (const float*)d_in[0];
  // d_in[1] = Wq, d_in[2] = Wk: dead code in the reference (einsum contracts them out)
  const float* Wv = (const float*)d_in[3];
  const float* Wo = (const float*)d_in[4];
  float* out = (float*)d_out;

  unsigned short* WvT = (unsigned short*)d_ws;                       //  4 MB
  unsigned short* RT  = WvT + (size_t)GENOMES * KVD * EMBED;         //  4 MB
  unsigned short* V   = RT  + (size_t)GENOMES * EMBED * KVD;         // 16 MB

  // prep: transpose/convert Wv, fold+transpose/convert Wo
  wvt_kernel<<<dim3(64, GENOMES), 256, 0, stream>>>(Wv, WvT);
  rt_kernel<<<dim3(64, GENOMES), 256, 0, stream>>>(Wo, RT);

  // GEMM1: V[g] (4096x256 bf16) = tensor[g] (4096x1024 fp32) @ WvT^T
  gemm_bt<true, true, M_PER_G, KVD, EMBED>
      <<<dim3((M_PER_G / 128) * (KVD / 64), GENOMES), 256, 0, stream>>>(tensor, WvT, V);

  // GEMM2: out[g] (4096x1024 fp32) = V[g] (4096x256 bf16) @ RT^T   (x64 folded into RT)
  gemm_bt<false, false, M_PER_G, EMBED, KVD>
      <<<dim3((M_PER_G / 128) * (EMBED / 64), GENOMES), 256, 0, stream>>>(V, RT, out);
}